// Round 9
// baseline (216.309 us; speedup 1.0000x reference)
//
#include <hip/hip_runtime.h>
#include <stdint.h>

#define DEVINL __device__ __forceinline__

typedef __attribute__((ext_vector_type(8))) __bf16 bf16x8;
typedef __attribute__((ext_vector_type(4))) float f32x4;
typedef __attribute__((ext_vector_type(2))) long longx2;

// ---------- helpers ----------
DEVINL unsigned short f2bf(float f) {
  union { float f; unsigned int u; } v; v.f = f;
  unsigned int u = v.u;
  return (unsigned short)((u + 0x7fffu + ((u >> 16) & 1u)) >> 16);  // RNE
}

// float -> OCP e4m3 byte via HW cvt (gfx950 = OCP semantics)
DEVINL unsigned char f2fp8(float f) {
  return (unsigned char)(__builtin_amdgcn_cvt_pk_fp8_f32(f, f, 0, false) & 0xff);
}

DEVINL float sigm(float x) { return __builtin_amdgcn_rcpf(1.f + __expf(-x)); }
// tanh = 1 - 2/(1+e^{2x}); inf-safe both directions.
DEVINL float tanh_(float x) {
  return 1.f - 2.f * __builtin_amdgcn_rcpf(1.f + __expf(2.f * x));
}

// K-window interleave for fp8 BK=64 tiles: within each 64-col window,
// element k sits at byte ((k&31)>>3)*16 + (k>>5)*8 + (k&7).
DEVINL int pcol(int gn) {
  return (gn & ~63) | ((((gn & 31) >> 3)) << 4) | (((gn >> 5) & 1) << 3) | (gn & 7);
}

// async global->LDS 16B per lane; lds base wave-uniform, HW scatters lane i to base+i*16
#define GLD_LDS16(gptr, lptr)                                                  \
  __builtin_amdgcn_global_load_lds(                                            \
      (__attribute__((address_space(1))) void*)(gptr),                         \
      (__attribute__((address_space(3))) void*)(lptr), 16, 0, 0)

// Stage-before-barrier pipeline (AITER "vmcnt never 0" pattern).
#define TOPBAR_4 asm volatile("s_waitcnt vmcnt(4) lgkmcnt(0)\n\ts_barrier" ::: "memory")
#define TOPBAR_1 asm volatile("s_waitcnt vmcnt(1) lgkmcnt(0)\n\ts_barrier" ::: "memory")
#define TOPBAR_0 asm volatile("s_waitcnt vmcnt(0) lgkmcnt(0)\n\ts_barrier" ::: "memory")
#define BOTBAR   asm volatile("s_waitcnt lgkmcnt(0)\n\ts_barrier" ::: "memory")

// XOR swizzle, 16B chunks, 4 chunks/row (zero-conflict pairing verified R3/R8).
DEVINL int swz_col(int c) { return ((c & 3) ^ ((c >> 3) & 3)) * 8; }   // bf16: shorts
DEVINL int swz16(int c) { return ((c & 3) ^ ((c >> 3) & 3)) * 16; }    // fp8: bytes

// ---------- fused prep: concat + weight cvt + hvec + q-init, grid-sectioned ----------
__global__ void prep_all(const float* __restrict__ obs, const float* __restrict__ act,
                         const float* __restrict__ W1, const float* __restrict__ Wih,
                         const float* __restrict__ W2, const float* __restrict__ Whh,
                         const float* __restrict__ hid, const float* __restrict__ bhh,
                         const float* __restrict__ bih, const float* __restrict__ b2,
                         unsigned short* __restrict__ A0, unsigned short* __restrict__ W1b,
                         unsigned char* __restrict__ Wih8, unsigned short* __restrict__ W2b,
                         float* __restrict__ hvec, float* __restrict__ qout) {
  const int bid = blockIdx.x, tid = threadIdx.x;
  if (bid < 2176) {
    // section A: concat(obs, act) -> bf16 [32768, 544]
    const int total = 32768 * 68;
    for (int c = bid * 256 + tid; c < total; c += 2176 * 256) {
      const int b = c / 68, c8 = c % 68;
      const float* src = (c8 < 64) ? (obs + (size_t)b * 512 + c8 * 8)
                                   : (act + (size_t)b * 32 + (c8 - 64) * 8);
      float4 f0 = *(const float4*)src;
      float4 f1 = *(const float4*)(src + 4);
      unsigned short u[8] = {f2bf(f0.x), f2bf(f0.y), f2bf(f0.z), f2bf(f0.w),
                             f2bf(f1.x), f2bf(f1.y), f2bf(f1.z), f2bf(f1.w)};
      *(uint4*)(A0 + (size_t)b * 544 + c8 * 8) = *(uint4*)u;
    }
  } else if (bid < 2176 + 1312) {
    // section B: weight conversion (one float4 per thread)
    const int i = (bid - 2176) * 256 + tid;
    if (i < 69632) {                       // W1 -> bf16
      float4 f = *(const float4*)(W1 + (size_t)i * 4);
      unsigned short u[4] = {f2bf(f.x), f2bf(f.y), f2bf(f.z), f2bf(f.w)};
      *(uint2*)(W1b + (size_t)i * 4) = *(uint2*)u;
    } else if (i < 69632 + 262144) {       // Wih -> fp8 e4m3 x16, K-interleaved layout
      const int off = i - 69632;
      const int row = off >> 7, col0 = (off & 127) * 4;
      float4 f = *(const float4*)(Wih + (size_t)off * 4);
      int pk = __builtin_amdgcn_cvt_pk_fp8_f32(f.x * 16.f, f.y * 16.f, 0, false);
      pk = __builtin_amdgcn_cvt_pk_fp8_f32(f.z * 16.f, f.w * 16.f, pk, true);
      *(unsigned int*)(Wih8 + (size_t)row * 512 + pcol(col0)) = (unsigned int)pk;
    } else {                               // W2 -> bf16
      const int off = i - 331776;
      float4 f = *(const float4*)(W2 + (size_t)off * 4);
      unsigned short u[4] = {f2bf(f.x), f2bf(f.y), f2bf(f.z), f2bf(f.w)};
      *(uint2*)(W2b + (size_t)off * 4) = *(uint2*)u;
    }
  } else if (bid < 2176 + 1312 + 512) {
    // section C: hvec[j] = dot(W_hh[j,:], hid) + b_hh[j] + b_ih[j]
    const int j = (bid - 3488) * 4 + (tid >> 6);
    const int lane = tid & 63;
    const float* w = Whh + (size_t)j * 512;
    float s = 0.f;
    for (int k = lane; k < 512; k += 64) s += w[k] * hid[k];
    for (int off = 32; off; off >>= 1) s += __shfl_down(s, off, 64);
    if (lane == 0) hvec[j] = s + bhh[j] + bih[j];
  } else {
    // section D: q init = b2 broadcast (atomic accumulation target)
    const int c = (bid - 4000) * 256 + tid;  // 262144 float4 stores
    const int row = c >> 3, j4 = c & 7;
    float4 b = *(const float4*)(b2 + j4 * 4);
    *(float4*)(qout + (size_t)row * 32 + j4 * 4) = b;
  }
}

// ---------- GEMM1: X8 = fp8(relu(A0 @ W1^T + b1) * 8), K-interleaved ----------
__global__ __launch_bounds__(256, 2) void gemm1_relu(
    const unsigned short* __restrict__ A0,   // [32768,544] bf16
    const unsigned short* __restrict__ W1b,  // [512,544] bf16
    const float* __restrict__ b1,            // [512]
    unsigned char* __restrict__ X8) {        // [32768,512] fp8 (x8, K-interleaved)
  constexpr int KT = 17, LD = 544;
  __shared__ __align__(16) unsigned short As[2][128 * 32];  // 16 KB
  __shared__ __align__(16) unsigned short Bs[2][128 * 32];  // 16 KB
  const int tid = threadIdx.x, wave = tid >> 6, lane = tid & 63;
  const int id = blockIdx.x, xcd = id & 7, slot = id >> 3;  // 1024 blocks
  const int m0 = (xcd * 32 + (slot >> 2)) * 128;            // 256 m-tiles
  const int n0 = (slot & 3) * 128;                          // 4 n-tiles
  const int wr = (wave >> 1) * 64, wc = (wave & 1) * 64;
  f32x4 acc[4][4] = {};

  const int c0 = tid, c1 = tid + 256;
  const unsigned short* pA0 = A0 + (size_t)(m0 + (c0 >> 2)) * LD + swz_col(c0);
  const unsigned short* pA1 = A0 + (size_t)(m0 + (c1 >> 2)) * LD + swz_col(c1);
  const unsigned short* pB0 = W1b + (size_t)(n0 + (c0 >> 2)) * LD + swz_col(c0);
  const unsigned short* pB1 = W1b + (size_t)(n0 + (c1 >> 2)) * LD + swz_col(c1);
  const int fr = lane & 15, q = lane >> 4;
  const int koff = (q ^ ((fr >> 1) & 3)) * 8;

#define STAGE1(buf)                                                            \
  do {                                                                         \
    GLD_LDS16(pA0, &As[(buf)][wave * 512]);                                    \
    GLD_LDS16(pA1, &As[(buf)][2048 + wave * 512]);                             \
    GLD_LDS16(pB0, &Bs[(buf)][wave * 512]);                                    \
    GLD_LDS16(pB1, &Bs[(buf)][2048 + wave * 512]);                             \
    pA0 += 32; pA1 += 32; pB0 += 32; pB1 += 32;                                \
  } while (0)

  STAGE1(0);
  for (int kt = 0; kt < KT; ++kt) {
    if (kt + 1 < KT) { STAGE1((kt + 1) & 1); TOPBAR_4; } else { TOPBAR_0; }
    const unsigned short* as = As[kt & 1];
    const unsigned short* bs = Bs[kt & 1];
    bf16x8 a[4], b[4];
#pragma unroll
    for (int i = 0; i < 4; ++i) a[i] = *(const bf16x8*)&as[(wr + i * 16 + fr) * 32 + koff];
#pragma unroll
    for (int j = 0; j < 4; ++j) b[j] = *(const bf16x8*)&bs[(wc + j * 16 + fr) * 32 + koff];
#pragma unroll
    for (int i = 0; i < 4; ++i)
#pragma unroll
      for (int j = 0; j < 4; ++j)
        acc[i][j] = __builtin_amdgcn_mfma_f32_16x16x32_bf16(a[i], b[j], acc[i][j], 0, 0, 0);
    BOTBAR;
  }
#undef STAGE1
  const int rbase = q * 4, cn = fr;
#pragma unroll
  for (int i = 0; i < 4; ++i)
#pragma unroll
    for (int j = 0; j < 4; ++j) {
      const int gn = n0 + wc + j * 16 + cn;
      const int pc = pcol(gn);  // K-interleaved column for gemm2's BK=64 tiles
      const float bias = b1[gn];
#pragma unroll
      for (int r = 0; r < 4; ++r) {
        const int gm = m0 + wr + i * 16 + rbase + r;
        float v = acc[i][j][r] + bias;
        v = v > 0.f ? v : 0.f;
        X8[(size_t)gm * 512 + pc] = f2fp8(v * 8.f);
      }
    }
}

// ---------- GEMM2 fp8 BK=64 + LSTM + fused GEMM3 partial (atomic q) ----------
// A = X8 (x8), B = Wih8 (x16); acc * (1/128) restores scale. h never hits HBM:
// it round-trips the dead K-loop LDS, partial q = h-slice @ W2-slice^T goes to
// global q via atomicAdd (q pre-initialized with b2 by prep).
__global__ __launch_bounds__(256, 4) void gemm23_lstm(
    const unsigned char* __restrict__ X8,    // [32768,512] fp8, K-interleaved
    const unsigned char* __restrict__ Wih8,  // [2048,512] fp8, K-interleaved
    const unsigned short* __restrict__ W2b,  // [32,512] bf16
    const float* __restrict__ hvec,          // [2048]
    const float* __restrict__ cell,          // [512]
    float* __restrict__ qout,                // [32768,32] fp32 (b2-initialized)
    float* __restrict__ hlast,               // [512] fp32 out
    float* __restrict__ clast) {             // [512] fp32 out
  constexpr int KT = 8;                      // BK = 64
  __shared__ __align__(16) unsigned char LDSB[4 * 8192];  // As[2] @0, Bs[2] @16384
#define AS2(buf) (LDSB + (buf) * 8192)
#define BS2(buf) (LDSB + 16384 + (buf) * 8192)
  unsigned short* hs = (unsigned short*)LDSB;  // [128][40] bf16, reused post-loop
  constexpr int LDH = 40;                      // padded: 80 B rows -> 2-way free
  const int tid = threadIdx.x, wave = tid >> 6, lane = tid & 63;
  const int id = blockIdx.x, xcd = id & 7, slot = id >> 3;  // 4096 blocks
  const int m0 = (xcd * 32 + (slot >> 4)) * 128;            // 256 m-tiles
  const int n0 = (slot & 15) * 32;                          // 16 h-col tiles
  const int wr = (wave >> 1) * 64, wc = (wave & 1) * 16;
  f32x4 acc[4][4] = {};                      // [row-tile][quadrant]

  const int c0 = tid, c1 = tid + 256;
  const unsigned char* pA0 = X8 + (size_t)(m0 + (c0 >> 2)) * 512 + swz16(c0);
  const unsigned char* pA1 = X8 + (size_t)(m0 + (c1 >> 2)) * 512 + swz16(c1);
  const unsigned char* pB0 =
      Wih8 + (size_t)((c0 >> 7) * 512 + n0 + ((c0 >> 2) & 31)) * 512 + swz16(c0);
  const unsigned char* pB1 =
      Wih8 + (size_t)((c1 >> 7) * 512 + n0 + ((c1 >> 2) & 31)) * 512 + swz16(c1);
  const int fr = lane & 15, q = lane >> 4;
  const int koff = (q ^ ((fr >> 1) & 3)) * 16;

#define STAGE2(buf)                                                            \
  do {                                                                         \
    GLD_LDS16(pA0, AS2(buf) + wave * 1024);                                    \
    GLD_LDS16(pA1, AS2(buf) + 4096 + wave * 1024);                             \
    GLD_LDS16(pB0, BS2(buf) + wave * 1024);                                    \
    GLD_LDS16(pB1, BS2(buf) + 4096 + wave * 1024);                             \
    pA0 += 64; pA1 += 64; pB0 += 64; pB1 += 64;                                \
  } while (0)

  STAGE2(0);
  for (int kt = 0; kt < KT; ++kt) {
    if (kt + 1 < KT) { STAGE2((kt + 1) & 1); TOPBAR_4; } else { TOPBAR_0; }
    const unsigned char* as = AS2(kt & 1);
    const unsigned char* bs = BS2(kt & 1);
    longx2 a[4], b[4];  // .x = k 0..31 operand, .y = k 32..63 operand
#pragma unroll
    for (int i = 0; i < 4; ++i)
      a[i] = *(const longx2*)&as[(wr + i * 16 + fr) * 64 + koff];
#pragma unroll
    for (int qd = 0; qd < 4; ++qd)
      b[qd] = *(const longx2*)&bs[qd * 2048 + (wc + fr) * 64 + koff];
#pragma unroll
    for (int i = 0; i < 4; ++i)
#pragma unroll
      for (int qd = 0; qd < 4; ++qd) {
        acc[i][qd] =
            __builtin_amdgcn_mfma_f32_16x16x32_fp8_fp8(a[i].x, b[qd].x, acc[i][qd], 0, 0, 0);
        acc[i][qd] =
            __builtin_amdgcn_mfma_f32_16x16x32_fp8_fp8(a[i].y, b[qd].y, acc[i][qd], 0, 0, 0);
      }
    BOTBAR;  // last one: all waves done reading As/Bs -> LDS reusable as hs
  }
#undef STAGE2

  // ---- LSTM epilogue: h -> hs (LDS), hlast/clast for row 32767 ----
  const int rbase = q * 4, cn = fr;
  const int gn = n0 + wc + cn;  // h column in [0,512)
  const float hv_i = hvec[gn];
  const float hv_f = hvec[gn + 512];
  const float hv_g = hvec[gn + 1024];
  const float hv_o = hvec[gn + 1536];
  const float cprev = cell[gn];
  constexpr float S = 1.f / 128.f;  // undo x8 (X) * x16 (Wih)
#pragma unroll
  for (int i = 0; i < 4; ++i)
#pragma unroll
    for (int r = 0; r < 4; ++r) {
      const int rl = wr + i * 16 + rbase + r;  // row-local 0..127
      float si = sigm(acc[i][0][r] * S + hv_i);
      float sf = sigm(acc[i][1][r] * S + hv_f);
      float tg = tanh_(acc[i][2][r] * S + hv_g);
      float so = sigm(acc[i][3][r] * S + hv_o);
      float cnew = sf * cprev + si * tg;
      float hnew = so * tanh_(cnew);
      hs[rl * LDH + (wc + cn)] = f2bf(hnew);
      if (m0 + rl == 32767) { hlast[gn] = hnew; clast[gn] = cnew; }
    }
  BOTBAR;  // hs visible to all waves

  // ---- fused GEMM3 partial: q[m0.., :] += h[:, n0:n0+32] @ W2[:, n0:n0+32]^T ----
  // wave w owns rows w*32..w*32+31 (2 tiles); j covers all 32 q-cols (2 tiles).
  f32x4 qacc[2][2] = {};
  bf16x8 wfrag[2];
#pragma unroll
  for (int jt = 0; jt < 2; ++jt)  // W2 slice, streamed L2-hot from global
    wfrag[jt] = *(const bf16x8*)(W2b + (size_t)(jt * 16 + fr) * 512 + n0 + q * 8);
#pragma unroll
  for (int i2 = 0; i2 < 2; ++i2) {
    bf16x8 afrag = *(const bf16x8*)&hs[(wave * 32 + i2 * 16 + fr) * LDH + q * 8];
#pragma unroll
    for (int jt = 0; jt < 2; ++jt)
      qacc[i2][jt] = __builtin_amdgcn_mfma_f32_16x16x32_bf16(afrag, wfrag[jt], qacc[i2][jt], 0, 0, 0);
  }
#pragma unroll
  for (int i2 = 0; i2 < 2; ++i2)
#pragma unroll
    for (int jt = 0; jt < 2; ++jt) {
      const int col = jt * 16 + fr;
#pragma unroll
      for (int r = 0; r < 4; ++r) {
        const int row = m0 + wave * 32 + i2 * 16 + q * 4 + r;
        atomicAdd(&qout[(size_t)row * 32 + col], qacc[i2][jt][r]);
      }
    }
#undef AS2
#undef BS2
}

// ---------- launch ----------
extern "C" void kernel_launch(void* const* d_in, const int* in_sizes, int n_in,
                              void* d_out, int out_size, void* d_ws, size_t ws_size,
                              hipStream_t stream) {
  const float* obs  = (const float*)d_in[0];
  const float* act  = (const float*)d_in[1];
  const float* hid  = (const float*)d_in[2];
  const float* cell = (const float*)d_in[3];
  const float* W1   = (const float*)d_in[4];
  const float* b1   = (const float*)d_in[5];
  const float* Wih  = (const float*)d_in[6];
  const float* bih  = (const float*)d_in[7];
  const float* Whh  = (const float*)d_in[8];
  const float* bhh  = (const float*)d_in[9];
  const float* W2   = (const float*)d_in[10];
  const float* b2   = (const float*)d_in[11];
  float* out = (float*)d_out;

  char* ws = (char*)d_ws;
  unsigned short* A0   = (unsigned short*)(ws);              // [B,544] bf16 (35,651,584 B)
  unsigned char*  X8   = (unsigned char*)(ws + 35651584);    // [B,512] fp8 (16,777,216 B)
  unsigned short* W1b  = (unsigned short*)(ws + 52428800);   // 557,056 B
  unsigned char*  Wih8 = (unsigned char*)(ws + 52985856);    // 1,048,576 B
  unsigned short* W2b  = (unsigned short*)(ws + 54034432);   // 32,768 B
  float*          hvec = (float*)(ws + 54067200);            // 8,192 B

  prep_all<<<5024, 256, 0, stream>>>(obs, act, W1, Wih, W2, Whh, hid, bhh, bih, b2,
                                     A0, W1b, Wih8, W2b, hvec, out);
  gemm1_relu<<<1024, 256, 0, stream>>>(A0, W1b, b1, X8);
  gemm23_lstm<<<4096, 256, 0, stream>>>(X8, Wih8, W2b, hvec, cell, out,
                                        out + 32768 * 32,
                                        out + 32768 * 32 + 512);
}